// Round 11
// baseline (261.375 us; speedup 1.0000x reference)
//
#include <hip/hip_runtime.h>
#include <hip/hip_bf16.h>

typedef unsigned short u16;
typedef unsigned int u32;

#define B_ 4
#define N_ 4096
#define C_ 256
#define NH_ 8
#define HD_ 32
#define L_ 9
#define P_ 64
#define T_ 4096
#define NEG_ (-1e30f)

typedef __attribute__((ext_vector_type(8))) short bf16x8;
typedef __attribute__((ext_vector_type(4))) float f32x4;

__device__ __forceinline__ float b2f(u16 u) {
    union { u32 i; float f; } v; v.i = ((u32)u) << 16; return v.f;
}
__device__ __forceinline__ u16 f2b(float f) {
    u32 x = __float_as_uint(f);
    u32 r = (x + 0x7fffu + ((x >> 16) & 1u)) >> 16;
    return (u16)r;
}
__device__ __forceinline__ short f2bs(float f) { return (short)f2b(f); }

// ---------------- prep: x->bf16, weights->bf16 (fused W), CPB MLP — one launch ----------------
__global__ __launch_bounds__(256) void prep_k(
    const float* __restrict__ x, const float* __restrict__ q_w, const float* __restrict__ kv_w,
    const float* __restrict__ sr_w, const float* __restrict__ proj_w,
    u16* __restrict__ xb, u16* __restrict__ wfused, u16* __restrict__ pwb,
    const float* __restrict__ table, const float* __restrict__ w1, const float* __restrict__ b1,
    const float* __restrict__ w2, const float* __restrict__ b2, float* __restrict__ cpb)
{
    __shared__ float w1s[512][2];
    __shared__ float b1s[512];
    __shared__ float w2s[8][512];
    int bid = blockIdx.x, tid = threadIdx.x;
    if (bid < 4096) {
        int i = bid * 256 + tid;
        float4 v = reinterpret_cast<const float4*>(x)[i];
        ushort4 o; o.x = f2b(v.x); o.y = f2b(v.y); o.z = f2b(v.z); o.w = f2b(v.w);
        reinterpret_cast<ushort4*>(xb)[i] = o;
    } else if (bid < 4416) {
        int i = (bid - 4096) * 256 + tid;
        const float* s; u16* d; int off;
        if (i < 16384)      { s = q_w;    d = wfused; off = i; }
        else if (i < 49152) { s = kv_w;   d = wfused; off = i; }
        else if (i < 65536) { s = sr_w;   d = wfused; off = i; }
        else                { s = proj_w; d = pwb;    off = i - 65536; }
        int soff = (i < 16384) ? i : (i < 49152) ? (i - 16384) : (i < 65536) ? (i - 49152) : (i - 65536);
        float4 v = reinterpret_cast<const float4*>(s)[soff];
        ushort4 o; o.x = f2b(v.x); o.y = f2b(v.y); o.z = f2b(v.z); o.w = f2b(v.w);
        reinterpret_cast<ushort4*>(d)[off] = o;
    } else {
        for (int i = tid; i < 512; i += 256) {
            w1s[i][0] = w1[i * 2]; w1s[i][1] = w1[i * 2 + 1]; b1s[i] = b1[i];
        }
        for (int i = tid; i < 4096; i += 256) w2s[i >> 9][i & 511] = w2[i];
        __syncthreads();
        int t = (bid - 4416) * 256 + tid;
        float t0 = table[t * 2], t1 = table[t * 2 + 1];
        float acc[8] = {};
        for (int j = 0; j < 512; ++j) {
            float h = fmaxf(t0 * w1s[j][0] + t1 * w1s[j][1] + b1s[j], 0.0f);
            #pragma unroll
            for (int hh = 0; hh < 8; ++hh) acc[hh] += h * w2s[hh][j];
        }
        #pragma unroll
        for (int hh = 0; hh < 8; ++hh) cpb[t * 8 + hh] = acc[hh] + b2[hh];
    }
}

// ---------------- LDS-staged MFMA GEMM ----------------
// MODE 0: 1-D grid. Blocks [0,768): fused kv/sr GEMM (bx=bid%12, by=bid/12).
//         Blocks [768, 768+2048): pool-bias precompute biasp[h][n][p] = cpb[rpi[n,p]*8+h].
// MODE 1: proj. 2-D grid (4, 256), block tile 64 rows x 64 cols.
template<int MODE>
__global__ __launch_bounds__(256) void gemm_big_k(
    const u16* __restrict__ A, const u16* __restrict__ W,
    const float* __restrict__ b0, const float* __restrict__ b1, const float* __restrict__ b2,
    float* __restrict__ kvk, u16* __restrict__ kvv, u16* __restrict__ xgb, float* __restrict__ pout,
    const int* __restrict__ rpi, const float* __restrict__ cpb, float* __restrict__ biasp)
{
    constexpr int RI = (MODE == 0) ? 4 : 1;
    int tid = threadIdx.x;
    int bx, by;
    if (MODE == 0) {
        int bid = blockIdx.x;
        if (bid >= 768) {
            int i = (bid - 768) * 256 + tid;
            int e0 = i * 4;
            int p = e0 & 63;
            int hn = e0 >> 6;
            int n = hn & 4095, h = hn >> 12;
            int4 idx4 = *reinterpret_cast<const int4*>(rpi + n * 64 + p);
            float4 o;
            o.x = cpb[(size_t)idx4.x * 8 + h];
            o.y = cpb[(size_t)idx4.y * 8 + h];
            o.z = cpb[(size_t)idx4.z * 8 + h];
            o.w = cpb[(size_t)idx4.w * 8 + h];
            *reinterpret_cast<float4*>(biasp + e0) = o;
            return;
        }
        bx = bid % 12; by = bid / 12;
    } else {
        bx = blockIdx.x; by = blockIdx.y;
    }
    __shared__ u16 Bs[64 * 264];
    int w = tid >> 6, lane = tid & 63;
    int quad = lane >> 4, l16 = lane & 15;
    int colBase = (MODE == 0 ? 256 : 0) + bx * 64;
    #pragma unroll
    for (int c = 0; c < 8; ++c) {
        int linear = c * 256 + tid;
        int col = linear >> 5, kc = linear & 31;
        uint4 v = *reinterpret_cast<const uint4*>(W + (size_t)(colBase + col) * 256 + kc * 8);
        *reinterpret_cast<uint4*>(&Bs[col * 264 + kc * 8]) = v;
    }
    __syncthreads();
    int rowBase = by * (RI * 64) + w * (RI * 16);
    f32x4 acc[RI][4] = {};
    const u16* aptr = A + (size_t)(rowBase + l16) * 256 + quad * 8;
    bf16x8 afc[RI];
    #pragma unroll
    for (int i = 0; i < RI; ++i) afc[i] = *reinterpret_cast<const bf16x8*>(aptr + (size_t)i * 16 * 256);
    #pragma unroll
    for (int k0 = 0; k0 < 256; k0 += 32) {
        bf16x8 afn[RI];
        if (k0 < 224) {
            #pragma unroll
            for (int i = 0; i < RI; ++i)
                afn[i] = *reinterpret_cast<const bf16x8*>(aptr + (size_t)i * 16 * 256 + k0 + 32);
        }
        #pragma unroll
        for (int j = 0; j < 4; ++j) {
            bf16x8 bfr = *reinterpret_cast<const bf16x8*>(&Bs[(j * 16 + l16) * 264 + k0 + quad * 8]);
            #pragma unroll
            for (int i = 0; i < RI; ++i)
                acc[i][j] = __builtin_amdgcn_mfma_f32_16x16x32_bf16(afc[i], bfr, acc[i][j], 0, 0, 0);
        }
        if (k0 < 224) {
            #pragma unroll
            for (int i = 0; i < RI; ++i) afc[i] = afn[i];
        }
    }
    int rng = (MODE == 0) ? (colBase >> 8) : 99;   // 1:kv-k 2:kv-v 3:sr
    float bj[4];
    #pragma unroll
    for (int j = 0; j < 4; ++j) {
        int gc = colBase + j * 16 + l16;
        if (MODE == 1)      bj[j] = b0[gc];
        else if (rng <= 2)  bj[j] = b1[gc - 256];
        else                bj[j] = b2[gc - 768];
    }
    #pragma unroll
    for (int i = 0; i < RI; ++i) {
        float vals[4][4];
        #pragma unroll
        for (int j = 0; j < 4; ++j)
            #pragma unroll
            for (int r = 0; r < 4; ++r) {
                float t = acc[i][j][r] + bj[j];
                if (MODE == 0 && rng == 3) t = 0.5f * t * (1.0f + erff(t * 0.70710678118654752f));
                vals[j][r] = t;
            }
        if (MODE == 0 && rng == 1) {
            #pragma unroll
            for (int hp = 0; hp < 2; ++hp)
                #pragma unroll
                for (int r = 0; r < 4; ++r) {
                    float s = vals[2*hp][r] * vals[2*hp][r] + vals[2*hp+1][r] * vals[2*hp+1][r];
                    s += __shfl_xor(s, 1); s += __shfl_xor(s, 2);
                    s += __shfl_xor(s, 4); s += __shfl_xor(s, 8);
                    float inv = 1.0f / fmaxf(sqrtf(s), 1e-12f);
                    vals[2*hp][r] *= inv; vals[2*hp+1][r] *= inv;
                }
        }
        #pragma unroll
        for (int j = 0; j < 4; ++j) {
            int gc = colBase + j * 16 + l16;
            #pragma unroll
            for (int r = 0; r < 4; ++r) {
                int row = rowBase + i * 16 + quad * 4 + r;
                if (MODE == 1)      pout[(size_t)row * 256 + gc] = vals[j][r];
                else if (rng == 1)  kvk[(size_t)row * 256 + gc - 256] = vals[j][r];
                else if (rng == 2)  kvv[(size_t)row * 256 + gc - 512] = f2b(vals[j][r]);
                else                xgb[(size_t)row * 256 + gc - 768] = f2b(vals[j][r]);
            }
        }
    }
}

// ---------------- fused avgpool+LN+kv_pool+k-norm: 2 blocks per (b,p), 512 blocks ----------------
__global__ __launch_bounds__(256) void poolkv_k(
    const u16* __restrict__ xgb, const float* __restrict__ g, const float* __restrict__ bta,
    const float* __restrict__ kv_w, const float* __restrict__ kv_b, float* __restrict__ kvp)
{
    __shared__ __align__(16) float xps[256];
    __shared__ float r1[4], r2[4];
    int bid = blockIdx.x;
    int tid = threadIdx.x;
    int bp = bid >> 1, half = bid & 1;
    int b = bp >> 6, p = bp & 63;
    int py = p >> 3, px = p & 7;
    int o = tid;
    float s = 0.0f;
    for (int sy = 0; sy < 8; ++sy)
        #pragma unroll
        for (int sx = 0; sx < 8; ++sx) {
            int pix = (py * 8 + sy) * 64 + px * 8 + sx;
            s += b2f(xgb[((size_t)(b * N_ + pix)) * C_ + o]);
        }
    float v = s * (1.0f / 64.0f);
    float s1 = v, s2 = v * v;
    #pragma unroll
    for (int off = 32; off >= 1; off >>= 1) { s1 += __shfl_xor(s1, off); s2 += __shfl_xor(s2, off); }
    int wv = o >> 6, ln = o & 63;
    if (ln == 0) { r1[wv] = s1; r2[wv] = s2; }
    __syncthreads();
    float S1 = r1[0] + r1[1] + r1[2] + r1[3];
    float S2 = r2[0] + r2[1] + r2[2] + r2[3];
    float mu = S1 * (1.0f / 256.0f);
    float var = S2 * (1.0f / 256.0f) - mu * mu;
    xps[o] = (v - mu) * rsqrtf(var + 1e-5f) * g[o] + bta[o];
    __syncthreads();
    int col = half * 256 + o;
    float a = kv_b[col];
    const float4* xp4 = (const float4*)xps;
    const float4* wrow = (const float4*)(kv_w + (size_t)col * 256);
    #pragma unroll 8
    for (int k4 = 0; k4 < 64; ++k4) {
        float4 xv = xp4[k4]; float4 wa = wrow[k4];
        a += xv.x * wa.x + xv.y * wa.y + xv.z * wa.z + xv.w * wa.w;
    }
    if (half == 0) {
        float ss = a * a;
        ss += __shfl_xor(ss, 1); ss += __shfl_xor(ss, 2); ss += __shfl_xor(ss, 4);
        ss += __shfl_xor(ss, 8); ss += __shfl_xor(ss, 16);
        a *= 1.0f / fmaxf(sqrtf(ss), 1e-12f);
    }
    kvp[(size_t)bp * 512 + col] = a;
}

// ---------------- MFMA fused attention: 2-tile loop; qs staged inside S_w (LDS ~35.4 KB) ----------------
__global__ __launch_bounds__(256) void attn_k(
    const u16* __restrict__ xb, const u16* __restrict__ qwb, const float* __restrict__ q_b,
    const float* __restrict__ kvk, const u16* __restrict__ kvv,
    const float* __restrict__ kvp, const float* __restrict__ biasp,
    const float* __restrict__ temp, const float* __restrict__ qe, const float* __restrict__ lt,
    const float* __restrict__ rpb, const float* __restrict__ lb,
    const float* __restrict__ slsin, u16* __restrict__ aob)
{
    __shared__ u16 kp_hi[64 * 40], kp_lo[64 * 40];
    __shared__ u16 vp_hi[32 * 72];
    __shared__ u16 ltb[16 * 32];
    __shared__ float S_w[4][16][76];      // cols 0..35 double as qs staging (per-wave temporal alias)
    __shared__ float rpb_s[9], lb_s[9];

    int bid = blockIdx.x;
    int tq = bid & 31, h = (bid >> 5) & 7, b = bid >> 8;
    int tid = threadIdx.x, wave = tid >> 6, lane = tid & 63;
    int quad = lane >> 4, l16 = lane & 15;

    {
        int p = tid >> 2, dc = (tid & 3) * 8;
        const float* src = kvp + ((size_t)(b * P_ + p)) * 512 + h * 32 + dc;
        float4 k0 = *(const float4*)(src), k1 = *(const float4*)(src + 4);
        float4 v0 = *(const float4*)(src + 256), v1 = *(const float4*)(src + 260);
        float kf[8] = {k0.x,k0.y,k0.z,k0.w,k1.x,k1.y,k1.z,k1.w};
        float vf[8] = {v0.x,v0.y,v0.z,v0.w,v1.x,v1.y,v1.z,v1.w};
        #pragma unroll
        for (int j = 0; j < 8; ++j) {
            u16 khi = f2b(kf[j]);
            kp_hi[p * 40 + dc + j] = khi;
            kp_lo[p * 40 + dc + j] = f2b(kf[j] - b2f(khi));
            vp_hi[(dc + j) * 72 + p] = f2b(vf[j]);
        }
    }
    for (int t = tid; t < 512; t += 256) {
        int l = t & 15, d = t >> 4;
        ltb[l * 32 + d] = (l < 9) ? f2b(lt[h * 288 + d * 9 + l]) : (u16)0;
    }
    if (tid < 9) { rpb_s[tid] = rpb[h * 9 + tid]; lb_s[tid] = lb[h * 9 + tid]; }
    float tsc = log1pf(expf(temp[h]));
    __syncthreads();

    const float* bp_h = biasp + (size_t)h * N_ * 64;

    for (int it = 0; it < 2; ++it) {
        int tile = tq * 2 + it;
        int n0w = tile * 64 + wave * 16;
        int y = tile;

        // ---- fused q-GEMM: 64x32 slice via 16 MFMA ----
        f32x4 qacc[2] = {};
        {
            const u16* xrow = xb + ((size_t)(b * N_ + n0w + l16)) * 256 + quad * 8;
            const u16* qwr  = qwb + ((size_t)(h * 32 + l16)) * 256 + quad * 8;
            #pragma unroll
            for (int k0 = 0; k0 < 256; k0 += 32) {
                bf16x8 ax = *(const bf16x8*)(xrow + k0);
                bf16x8 bw0 = *(const bf16x8*)(qwr + k0);
                bf16x8 bw1 = *(const bf16x8*)(qwr + 16 * 256 + k0);
                qacc[0] = __builtin_amdgcn_mfma_f32_16x16x32_bf16(ax, bw0, qacc[0], 0, 0, 0);
                qacc[1] = __builtin_amdgcn_mfma_f32_16x16x32_bf16(ax, bw1, qacc[1], 0, 0, 0);
            }
        }
        {
            float qb0 = q_b[h * 32 + l16], qb1 = q_b[h * 32 + 16 + l16];
            float qe0 = qe[h * 32 + l16],  qe1 = qe[h * 32 + 16 + l16];
            #pragma unroll
            for (int r = 0; r < 4; ++r) {
                int p = quad * 4 + r;
                float v0 = qacc[0][r] + qb0, v1 = qacc[1][r] + qb1;
                float s = v0 * v0 + v1 * v1;
                s += __shfl_xor(s, 1); s += __shfl_xor(s, 2);
                s += __shfl_xor(s, 4); s += __shfl_xor(s, 8);
                float inv = 1.0f / fmaxf(sqrtf(s), 1e-12f);
                v0 *= inv; v1 *= inv;
                float sc = tsc * slsin[n0w + p];
                S_w[wave][p][l16]      = (v0 + qe0) * sc;   // qs staging (alias)
                S_w[wave][p][16 + l16] = (v1 + qe1) * sc;
            }
        }
        // ---- rebuild per-lane fragments (A-layout) from staged qs ----
        bf16x8 qs_hi, qs_lo, qn_b;
        float qsr[8];
        {
            *(float4*)&qsr[0] = *(const float4*)&S_w[wave][l16][quad * 8];
            *(float4*)&qsr[4] = *(const float4*)&S_w[wave][l16][quad * 8 + 4];
            float invs = 1.0f / (tsc * slsin[n0w + l16]);
            const float* qep = qe + h * 32 + quad * 8;
            float4 e0 = *(const float4*)qep, e1 = *(const float4*)(qep + 4);
            float ef[8] = {e0.x,e0.y,e0.z,e0.w,e1.x,e1.y,e1.z,e1.w};
            #pragma unroll
            for (int j = 0; j < 8; ++j) {
                u16 hi = f2b(qsr[j]);
                qs_hi[j] = (short)hi;
                qs_lo[j] = f2bs(qsr[j] - b2f(hi));
                qn_b[j]  = f2bs(qsr[j] * invs - ef[j]);
            }
        }
        // ---- pool logits (12 MFMA, compensated) + precomputed bias (overwrites qs staging) ----
        #pragma unroll
        for (int jt = 0; jt < 4; ++jt) {
            bf16x8 bh = *(const bf16x8*)&kp_hi[(jt * 16 + l16) * 40 + quad * 8];
            bf16x8 bl = *(const bf16x8*)&kp_lo[(jt * 16 + l16) * 40 + quad * 8];
            f32x4 a = {};
            a = __builtin_amdgcn_mfma_f32_16x16x32_bf16(qs_lo, bh, a, 0, 0, 0);
            a = __builtin_amdgcn_mfma_f32_16x16x32_bf16(qs_hi, bl, a, 0, 0, 0);
            a = __builtin_amdgcn_mfma_f32_16x16x32_bf16(qs_hi, bh, a, 0, 0, 0);
            #pragma unroll
            for (int r = 0; r < 4; ++r) {
                int pix = quad * 4 + r;
                int n = n0w + pix;
                S_w[wave][pix][jt * 16 + l16] = a[r] + bp_h[(size_t)n * 64 + jt * 16 + l16];
            }
        }
        // ---- learnable-token logits (1 MFMA) ----
        f32x4 accL;
        {
            bf16x8 ltf = *(const bf16x8*)&ltb[l16 * 32 + quad * 8];
            f32x4 z = {};
            accL = __builtin_amdgcn_mfma_f32_16x16x32_bf16(qn_b, ltf, z, 0, 0, 0);
        }
        // ---- local 3x3 logits: register qs + cross-quad shuffle reduce ----
        #pragma unroll
        for (int l = 0; l < 9; ++l) {
            int n = n0w + l16, x = n & 63;
            int ny = y + l / 3 - 1, nx = x + (l % 3) - 1;
            bool ok = ((unsigned)ny < 64u) && ((unsigned)nx < 64u);
            int nn = ok ? ny * 64 + nx : n;
            const float4* kb = (const float4*)(kvk + ((size_t)(b * N_ + nn)) * 256 + h * 32 + quad * 8);
            float4 k0v = kb[0], k1v = kb[1];
            float part = qsr[0]*k0v.x + qsr[1]*k0v.y + qsr[2]*k0v.z + qsr[3]*k0v.w
                       + qsr[4]*k1v.x + qsr[5]*k1v.y + qsr[6]*k1v.z + qsr[7]*k1v.w;
            part += __shfl_xor(part, 16);
            part += __shfl_xor(part, 32);
            if (quad == 0) S_w[wave][l16][64 + l] = ok ? (part + rpb_s[l]) : NEG_;
        }
        // ---- re-init NEG pad ----
        if (quad == 0) { S_w[wave][l16][73] = NEG_; S_w[wave][l16][74] = NEG_; S_w[wave][l16][75] = NEG_; }
        // ---- softmax over 73 (4 lanes per pixel, 19 cols each) ----
        {
            int pix = lane >> 2, c0 = (lane & 3) * 19;
            float vals[19]; float mx = NEG_;
            #pragma unroll
            for (int i = 0; i < 19; ++i) { vals[i] = S_w[wave][pix][c0 + i]; mx = fmaxf(mx, vals[i]); }
            mx = fmaxf(mx, __shfl_xor(mx, 1));
            mx = fmaxf(mx, __shfl_xor(mx, 2));
            float sm = 0.0f;
            #pragma unroll
            for (int i = 0; i < 19; ++i) { vals[i] = expf(vals[i] - mx); sm += vals[i]; }
            sm += __shfl_xor(sm, 1); sm += __shfl_xor(sm, 2);
            float inv = 1.0f / sm;
            #pragma unroll
            for (int i = 0; i < 19; ++i) S_w[wave][pix][c0 + i] = vals[i] * inv;
        }
        // ---- combined local weights overwrite S_w cols 64..72 ----
        if (l16 < 9) {
            #pragma unroll
            for (int r = 0; r < 4; ++r) {
                int pix = quad * 4 + r;
                int n = n0w + pix, x = n & 63;
                int ny = y + l16 / 3 - 1, nx = x + (l16 % 3) - 1;
                bool ok = ((unsigned)ny < 64u) && ((unsigned)nx < 64u);
                float prev = S_w[wave][pix][64 + l16];
                S_w[wave][pix][64 + l16] = ok ? (accL[r] + lb_s[l16] + prev) : 0.0f;
            }
        }
        // ---- PV (8 MFMA: (w_hi + w_lo) x v_hi) ----
        f32x4 accO[2] = {};
        #pragma unroll
        for (int kc = 0; kc < 2; ++kc) {
            float wf[8];
            *(float4*)&wf[0] = *(const float4*)&S_w[wave][l16][kc * 32 + quad * 8];
            *(float4*)&wf[4] = *(const float4*)&S_w[wave][l16][kc * 32 + quad * 8 + 4];
            bf16x8 w_hi, w_lo;
            #pragma unroll
            for (int j = 0; j < 8; ++j) {
                u16 hi = f2b(wf[j]);
                w_hi[j] = (short)hi;
                w_lo[j] = f2bs(wf[j] - b2f(hi));
            }
            #pragma unroll
            for (int nt = 0; nt < 2; ++nt) {
                bf16x8 vh = *(const bf16x8*)&vp_hi[(nt * 16 + l16) * 72 + kc * 32 + quad * 8];
                accO[nt] = __builtin_amdgcn_mfma_f32_16x16x32_bf16(w_lo, vh, accO[nt], 0, 0, 0);
                accO[nt] = __builtin_amdgcn_mfma_f32_16x16x32_bf16(w_hi, vh, accO[nt], 0, 0, 0);
            }
        }
        // ---- local-V: shared neighbor columns per quad (18 cols x 2 dims) ----
        {
            int xq0 = wave * 16 + quad * 4;
            #pragma unroll
            for (int dy = -1; dy <= 1; ++dy) {
                int ny = y + dy;
                bool rowOK = ((unsigned)ny < 64u);
                #pragma unroll
                for (int c = 0; c < 6; ++c) {
                    int xc = xq0 - 1 + c;
                    bool ok = rowOK && ((unsigned)xc < 64u);
                    int nn = ok ? ny * 64 + xc : 0;
                    const u16* vb = kvv + ((size_t)(b * N_ + nn)) * 256 + h * 32;
                    float v0 = b2f(vb[l16]);
                    float v1 = b2f(vb[16 + l16]);
                    #pragma unroll
                    for (int r = 0; r < 4; ++r) {
                        int dxr = c - 1 - r;
                        if (dxr >= -1 && dxr <= 1) {
                            int l = (dy + 1) * 3 + dxr + 1;
                            float aw = S_w[wave][quad * 4 + r][64 + l];
                            accO[0][r] += aw * v0;
                            accO[1][r] += aw * v1;
                        }
                    }
                }
            }
        }
        #pragma unroll
        for (int nt = 0; nt < 2; ++nt)
            #pragma unroll
            for (int r = 0; r < 4; ++r) {
                int n = n0w + quad * 4 + r;
                aob[((size_t)(b * N_ + n)) * C_ + h * 32 + nt * 16 + l16] = f2b(accO[nt][r]);
            }
    }
}

extern "C" void kernel_launch(void* const* d_in, const int* in_sizes, int n_in,
                              void* d_out, int out_size, void* d_ws, size_t ws_size,
                              hipStream_t stream) {
    const float* x      = (const float*)d_in[0];
    const int*   rpi    = (const int*)d_in[1];
    const float* table  = (const float*)d_in[2];
    const float* q_w    = (const float*)d_in[3];
    const float* q_b    = (const float*)d_in[4];
    const float* kv_w   = (const float*)d_in[5];
    const float* kv_b   = (const float*)d_in[6];
    const float* temp   = (const float*)d_in[7];
    const float* qe     = (const float*)d_in[8];
    const float* proj_w = (const float*)d_in[9];
    const float* proj_b = (const float*)d_in[10];
    const float* sr_w   = (const float*)d_in[11];
    const float* sr_b   = (const float*)d_in[12];
    const float* norm_g = (const float*)d_in[13];
    const float* norm_b = (const float*)d_in[14];
    const float* cpb1_w = (const float*)d_in[15];
    const float* cpb1_b = (const float*)d_in[16];
    const float* cpb2_w = (const float*)d_in[17];
    const float* cpb2_b = (const float*)d_in[18];
    const float* rpb    = (const float*)d_in[19];
    const float* lt     = (const float*)d_in[20];
    const float* lb     = (const float*)d_in[21];
    const float* sls    = (const float*)d_in[22];

    float* ws   = (float*)d_ws;
    float* kvk  = ws;                                   // B*N*C fp32 (k, l2normed)
    float* kvp  = kvk + (size_t)B_ * N_ * C_;           // B*P*2C fp32
    float* cpb  = kvp + (size_t)B_ * P_ * 2 * C_;       // T*NH fp32
    float* bia  = cpb + (size_t)T_ * NH_;               // NH*N*P fp32
    u16*   xb   = (u16*)(bia + (size_t)NH_ * N_ * P_);  // B*N*C bf16
    u16*   wfb  = xb  + (size_t)B_ * N_ * C_;           // 1024*256 bf16 (q;kv;sr)
    u16*   pwb  = wfb + (size_t)1024 * C_;              // C*C bf16
    u16*   kvv  = pwb + (size_t)C_ * C_;                // B*N*C bf16 (v)
    u16*   xgb  = kvv + (size_t)B_ * N_ * C_;           // B*N*C bf16 (gelu out; reused as attn out)
    u16*   aob  = xgb;

    dim3 blk(256);

    prep_k<<<dim3(4432), blk, 0, stream>>>(x, q_w, kv_w, sr_w, proj_w, xb, wfb, pwb,
                                           table, cpb1_w, cpb1_b, cpb2_w, cpb2_b, cpb);
    gemm_big_k<0><<<dim3(768 + 2048), blk, 0, stream>>>(xb, wfb, nullptr, kv_b, sr_b, kvk, kvv, xgb,
                                                        nullptr, rpi, cpb, bia);
    poolkv_k<<<dim3(B_ * P_ * 2), blk, 0, stream>>>(xgb, norm_g, norm_b, kv_w, kv_b, kvp);
    attn_k<<<dim3(B_ * NH_ * 32), blk, 0, stream>>>(xb, wfb, q_b, kvk, kvv, kvp, bia,
                                                    temp, qe, lt, rpb, lb, sls, aob);
    gemm_big_k<1><<<dim3(4, 256), blk, 0, stream>>>(aob, pwb, proj_b, nullptr, nullptr,
                                                    nullptr, nullptr, nullptr, (float*)d_out,
                                                    nullptr, nullptr, nullptr);
}